// Round 15
// baseline (80678.809 us; speedup 1.0000x reference)
//
#include <hip/hip_runtime.h>

// GRUModel: 2-layer GRU (T=16384, IN=512, H=1024) + BatchNorm(train) + FC(H->1)
//
// Persistent kernel, 64 blocks x 512 threads (8 waves): blocks 0..31 layer 0,
// blocks 32..63 layer 1; wave owns 4 contiguous channels (weights in VGPRs,
// v_dot2_f32_f16). Cross-block exchange via AGENT-scope relaxed atomics;
// consumers poll u64 granules against the f16-NaN sentinel 0x7F7F7F7F.
//
// CONFIRMED LAW (R4-R14): the period is an ARRIVAL-LATENCY floor (store ->
// cross-XCD visibility -> detect); dur tracks coherent-path spin probe issue
// volume per spinning POPULATION; spin form/placement (R10's) is optimal;
// preamble work (h1 poll + ih dots) is fully hidden under h2 arrival (R14).
// Wins: R9 (h2 spinners 256->64, -24%), R10 (h1 spinners 256->64, -2.7%).
//
// ROUND-15: the last lever in the proven family — ANOTHER 2x POPULATION CUT.
// 8-wave blocks halve each vector's spinning population (64 -> 32 wave-0s)
// and halve the consumer convoy units, with per-wave work, weights, stores,
// spin form, and placement all byte-identical to R10. L1's per-wave h1 poll
// keeps its population (256, usually-ready) and its arrival-throttle role.

#define TT 16384
#define IND 512
#define HD 1024

typedef _Float16 h2_t __attribute__((ext_vector_type(2)));
typedef unsigned long long u64;

static __device__ __forceinline__ float fdot2f(h2_t a, h2_t b, float c) {
  return __builtin_amdgcn_fdot2(a, b, c, false);
}
static __device__ __forceinline__ h2_t cvt2(float a, float b) {
  h2_t r; r.x = (_Float16)a; r.y = (_Float16)b; return r;
}
static __device__ __forceinline__ float sigm(float v) { return 1.f / (1.f + __expf(-v)); }
static __device__ __forceinline__ float tanh_f(float v) {
  v = fminf(fmaxf(v, -15.f), 15.f);
  float e = __expf(2.f * v);
  return (e - 1.f) / (e + 1.f);
}

// Reduce 4 per-lane partials across 64 lanes. Returns (R,Z,Nx,Nh) totals in
// all lanes. 11 cross-lane ops instead of 24 (pair-merge butterfly).
static __device__ __forceinline__ float4 reduce4(float aR, float aZ, float aNx,
                                                 float aNh, int lane) {
  const bool s1 = lane & 1;
  float x1 = s1 ? aZ : aR, y1 = s1 ? aR : aZ;
  x1 += __shfl_xor(y1, 1);
  float x2 = s1 ? aNh : aNx, y2 = s1 ? aNx : aNh;
  x2 += __shfl_xor(y2, 1);
  const bool s2 = lane & 2;
  float z = s2 ? x2 : x1, w = s2 ? x1 : x2;
  z += __shfl_xor(w, 2);
  z += __shfl_xor(z, 4);
  z += __shfl_xor(z, 8);
  z += __shfl_xor(z, 16);
  z += __shfl_xor(z, 32);
  return make_float4(__shfl(z, 0), __shfl(z, 1), __shfl(z, 2), __shfl(z, 3));
}

static __device__ __forceinline__ u64 pack4(float h0, float h1,
                                            float h2, float h3) {
  unsigned lo = (unsigned)__builtin_bit_cast(unsigned short, (_Float16)h0) |
                ((unsigned)__builtin_bit_cast(unsigned short, (_Float16)h1) << 16);
  unsigned hi = (unsigned)__builtin_bit_cast(unsigned short, (_Float16)h2) |
                ((unsigned)__builtin_bit_cast(unsigned short, (_Float16)h3) << 16);
  return (u64)lo | ((u64)hi << 32);
}

static __device__ __forceinline__ void unpack8(const u64 hv[4], h2_t hh[8]) {
#pragma unroll
  for (int i = 0; i < 4; ++i) {
    hh[2 * i]     = __builtin_bit_cast(h2_t, (unsigned)hv[i]);
    hh[2 * i + 1] = __builtin_bit_cast(h2_t, (unsigned)(hv[i] >> 32));
  }
}

static __device__ __forceinline__ u64 aload(const u64* p) {
  return __hip_atomic_load(p, __ATOMIC_RELAXED, __HIP_MEMORY_SCOPE_AGENT);
}

// Single-probe spin (R9/R10 proven form): all-4 reload until none sentinel.
static __device__ __forceinline__ void spin4(const u64* p, u64 v[4]) {
  bool ok;
  do {
    ok = true;
#pragma unroll
    for (int i = 0; i < 4; ++i) {
      v[i] = aload(p + i);
      ok = ok & ((unsigned)v[i] != 0x7F7F7F7Fu);
    }
  } while (__any(!ok));
}

__launch_bounds__(512, 1)
__global__ void gru_persistent(
    const float* __restrict__ x,
    const float* __restrict__ wih0, const float* __restrict__ whh0,
    const float* __restrict__ bih0, const float* __restrict__ bhh0,
    const float* __restrict__ wih1, const float* __restrict__ whh1,
    const float* __restrict__ bih1, const float* __restrict__ bhh1,
    u64* h1u, u64* h2u, float* sums)
{
  __shared__ u64 bcast[2][256];  // double-buffered broadcast slab (both layers)
  const int bid = blockIdx.x;
  const int tid = threadIdx.x;
  const int wave = tid >> 6;
  const int lane = tid & 63;

  if (bid < 32) {
    // ---------------- layer 0 : wave owns channels ch..ch+3 ----------------
    const int ch = bid * 32 + wave * 4;
    h2_t Wx[4][3][4];   // x-part: 8 f16 per gate per channel
    h2_t Wh[4][3][8];   // h-part: 16 f16 per gate per channel
    float bRv[4], bZv[4], bNxv[4], bNhv[4];
#pragma unroll
    for (int cc = 0; cc < 4; ++cc) {
      const int c = ch + cc;
#pragma unroll
      for (int g = 0; g < 3; ++g) {
        const float* pr = wih0 + (size_t)(g * HD + c) * IND + 8 * lane;
#pragma unroll
        for (int j = 0; j < 4; ++j) Wx[cc][g][j] = cvt2(pr[2 * j], pr[2 * j + 1]);
        const float* ph = whh0 + (size_t)(g * HD + c) * HD + 16 * lane;
#pragma unroll
        for (int j = 0; j < 8; ++j) Wh[cc][g][j] = cvt2(ph[2 * j], ph[2 * j + 1]);
      }
      bRv[cc]  = bih0[c] + bhh0[c];
      bZv[cc]  = bih0[HD + c] + bhh0[HD + c];
      bNxv[cc] = bih0[2 * HD + c];
      bNhv[cc] = bhh0[2 * HD + c];
    }
    float hprev[4] = {0.f, 0.f, 0.f, 0.f};
    // software-pipelined x row
    const float* px0 = x + 8 * lane;
    float4 xa = *(const float4*)px0;
    float4 xb = *(const float4*)(px0 + 4);
    for (int t = 0; t < TT; ++t) {
      h2_t xv[4];
      xv[0] = cvt2(xa.x, xa.y); xv[1] = cvt2(xa.z, xa.w);
      xv[2] = cvt2(xb.x, xb.y); xv[3] = cvt2(xb.z, xb.w);
      if (t + 1 < TT) {
        const float* pn = x + (size_t)(t + 1) * IND + 8 * lane;
        xa = *(const float4*)pn;
        xb = *(const float4*)(pn + 4);
      }
      // x-part partials (off critical path, all waves; also the arrival
      // throttle before wave0's spin)
      float aR[4], aZ[4], aNx[4], aNh[4];
#pragma unroll
      for (int cc = 0; cc < 4; ++cc) {
        float r = 0.f, z = 0.f, n = 0.f;
#pragma unroll
        for (int j = 0; j < 4; ++j) {
          r = fdot2f(Wx[cc][0][j], xv[j], r);
          z = fdot2f(Wx[cc][1][j], xv[j], z);
          n = fdot2f(Wx[cc][2][j], xv[j], n);
        }
        aR[cc] = r; aZ[cc] = z; aNx[cc] = n; aNh[cc] = 0.f;
      }
      // h1[t-1] (slot t; slot 0 pre-zeroed): single-wave spin + broadcast;
      // waves 1-7 park at the barrier.
      u64 hv[4];
      if (wave == 0) {
        spin4(h1u + (size_t)t * 256 + 4 * lane, hv);
#pragma unroll
        for (int i = 0; i < 4; ++i) bcast[t & 1][4 * lane + i] = hv[i];
      }
      __syncthreads();
      if (wave != 0) {
#pragma unroll
        for (int i = 0; i < 4; ++i) hv[i] = bcast[t & 1][4 * lane + i];
      }
      h2_t hh[8];
      unpack8(hv, hh);
#pragma unroll
      for (int cc = 0; cc < 4; ++cc) {
        float r = aR[cc], z = aZ[cc], n = aNh[cc];
#pragma unroll
        for (int j = 0; j < 8; ++j) {
          r = fdot2f(Wh[cc][0][j], hh[j], r);
          z = fdot2f(Wh[cc][1][j], hh[j], z);
          n = fdot2f(Wh[cc][2][j], hh[j], n);
        }
        aR[cc] = r; aZ[cc] = z; aNh[cc] = n;
      }
      float hn[4];
#pragma unroll
      for (int cc = 0; cc < 4; ++cc) {
        float4 s = reduce4(aR[cc], aZ[cc], aNx[cc], aNh[cc], lane);
        float r = sigm(s.x + bRv[cc]);
        float zz = sigm(s.y + bZv[cc]);
        float n = tanh_f(s.z + bNxv[cc] + r * (s.w + bNhv[cc]));
        hn[cc] = (1.f - zz) * n + zz * hprev[cc];
        hprev[cc] = hn[cc];
      }
      if (lane == 0) {
        u64 pk = pack4(hn[0], hn[1], hn[2], hn[3]);
        __hip_atomic_store(h1u + (size_t)(t + 1) * 256 + (ch >> 2), pk,
                           __ATOMIC_RELAXED, __HIP_MEMORY_SCOPE_AGENT);
      }
    }
  } else {
    // ---------------- layer 1 : wave owns channels ch..ch+3 ----------------
    const int ch = (bid - 32) * 32 + wave * 4;
    // parts: 0=r_ih 1=r_hh 2=z_ih 3=z_hh 4=n_ih 5=n_hh ; 16-f16 slice each
    h2_t W[4][6][8];
    float bRv[4], bZv[4], bNxv[4], bNhv[4];
#pragma unroll
    for (int cc = 0; cc < 4; ++cc) {
      const int c = ch + cc;
#pragma unroll
      for (int g = 0; g < 3; ++g) {
        const float* pi = wih1 + (size_t)(g * HD + c) * HD + 16 * lane;
        const float* ph = whh1 + (size_t)(g * HD + c) * HD + 16 * lane;
#pragma unroll
        for (int j = 0; j < 8; ++j) {
          W[cc][2 * g][j]     = cvt2(pi[2 * j], pi[2 * j + 1]);
          W[cc][2 * g + 1][j] = cvt2(ph[2 * j], ph[2 * j + 1]);
        }
      }
      bRv[cc]  = bih1[c] + bhh1[c];
      bZv[cc]  = bih1[HD + c] + bhh1[HD + c];
      bNxv[cc] = bih1[2 * HD + c];
      bNhv[cc] = bhh1[2 * HD + c];
    }
    float hprev[4] = {0.f, 0.f, 0.f, 0.f};
    float ssum[4] = {0.f, 0.f, 0.f, 0.f};
    float ssq[4] = {0.f, 0.f, 0.f, 0.f};
    for (int t = 1; t <= TT; ++t) {
      // poll h1[t-1] (slot t) — per-wave baseline form (usually 1 iteration;
      // unchanged population, doubles as arrival throttle)
      const u64* p1 = h1u + (size_t)t * 256 + 4 * lane;
      u64 va[4];
      bool ok;
      do {
        ok = true;
#pragma unroll
        for (int i = 0; i < 4; ++i) {
          va[i] = aload(p1 + i);
          ok = ok & ((unsigned)va[i] != 0x7F7F7F7Fu);
        }
      } while (__any(!ok));
      h2_t g1[8];
      unpack8(va, g1);
      float aR[4], aZ[4], aNx[4], aNh[4];
#pragma unroll
      for (int cc = 0; cc < 4; ++cc) {
        float r = 0.f, z = 0.f, n = 0.f;
#pragma unroll
        for (int j = 0; j < 8; ++j) {
          r = fdot2f(W[cc][0][j], g1[j], r);
          z = fdot2f(W[cc][2][j], g1[j], z);
          n = fdot2f(W[cc][4][j], g1[j], n);
        }
        aR[cc] = r; aZ[cc] = z; aNx[cc] = n; aNh[cc] = 0.f;
      }
      // h2[t-2] (slot t-1): single-wave spin (R10 form/placement) + broadcast;
      // waves 1-7 park at the barrier.
      u64 vb[4];
      if (wave == 0) {
        spin4(h2u + (size_t)(t - 1) * 256 + 4 * lane, vb);
#pragma unroll
        for (int i = 0; i < 4; ++i) bcast[t & 1][4 * lane + i] = vb[i];
      }
      __syncthreads();
      if (wave != 0) {
#pragma unroll
        for (int i = 0; i < 4; ++i) vb[i] = bcast[t & 1][4 * lane + i];
      }
      h2_t g2[8];
      unpack8(vb, g2);
#pragma unroll
      for (int cc = 0; cc < 4; ++cc) {
        float r = aR[cc], z = aZ[cc], n = aNh[cc];
#pragma unroll
        for (int j = 0; j < 8; ++j) {
          r = fdot2f(W[cc][1][j], g2[j], r);
          z = fdot2f(W[cc][3][j], g2[j], z);
          n = fdot2f(W[cc][5][j], g2[j], n);
        }
        aR[cc] = r; aZ[cc] = z; aNh[cc] = n;
      }
      float hn[4];
#pragma unroll
      for (int cc = 0; cc < 4; ++cc) {
        float4 s = reduce4(aR[cc], aZ[cc], aNx[cc], aNh[cc], lane);
        float r = sigm(s.x + bRv[cc]);
        float zz = sigm(s.y + bZv[cc]);
        float n = tanh_f(s.z + bNxv[cc] + r * (s.w + bNhv[cc]));
        hn[cc] = (1.f - zz) * n + zz * hprev[cc];
        hprev[cc] = hn[cc];
        ssum[cc] += hn[cc];
        ssq[cc] += hn[cc] * hn[cc];
      }
      if (lane == 0) {
        u64 pk = pack4(hn[0], hn[1], hn[2], hn[3]);
        __hip_atomic_store(h2u + (size_t)t * 256 + (ch >> 2), pk,
                           __ATOMIC_RELAXED, __HIP_MEMORY_SCOPE_AGENT);
      }
    }
    if (lane == 0) {
#pragma unroll
      for (int cc = 0; cc < 4; ++cc) {
        sums[ch + cc] = ssum[cc];
        sums[HD + ch + cc] = ssq[cc];
      }
    }
  }
}

// y[t] = K + sum_c h2[t,c]*A[c];  A = rsqrt(var+eps)*gamma*fc_w,
// K = fc_b + sum_c (beta*fc_w - mu*A)
__launch_bounds__(256)
__global__ void fc_bn_kernel(const unsigned* __restrict__ h2u, const float* __restrict__ sums,
                             const float* __restrict__ gamma, const float* __restrict__ beta,
                             const float* __restrict__ fcw, const float* __restrict__ fcb,
                             float* __restrict__ out)
{
  const int tid = threadIdx.x;
  const int wave = tid >> 6;
  const int lane = tid & 63;
  float A[16];
  float kp = 0.f;
#pragma unroll
  for (int j = 0; j < 16; ++j) {
    const int c = 16 * lane + j;
    float mu = sums[c] * (1.f / TT);
    float var = fmaxf(sums[HD + c] * (1.f / TT) - mu * mu, 0.f);
    float rs = rsqrtf(var + 1e-5f);
    float a = rs * gamma[c] * fcw[c];
    A[j] = a;
    kp += beta[c] * fcw[c] - mu * a;
  }
#pragma unroll
  for (int m = 32; m >= 1; m >>= 1) kp += __shfl_xor(kp, m);
  const float K = kp + fcb[0];
  const int tbase = (blockIdx.x * 4 + wave) * 16;
  for (int mm = 0; mm < 16; ++mm) {
    const int t = tbase + mm;
    const unsigned* p = h2u + (size_t)(t + 1) * 512 + 8 * lane;
    float d = 0.f;
#pragma unroll
    for (int j = 0; j < 8; ++j) {
      h2_t hp = __builtin_bit_cast(h2_t, p[j]);
      d += (float)hp.x * A[2 * j] + (float)hp.y * A[2 * j + 1];
    }
#pragma unroll
    for (int m = 32; m >= 1; m >>= 1) d += __shfl_xor(d, m);
    if (lane == 0) out[t] = K + d;
  }
}

extern "C" void kernel_launch(void* const* d_in, const int* in_sizes, int n_in,
                              void* d_out, int out_size, void* d_ws, size_t ws_size,
                              hipStream_t stream) {
  const float* x    = (const float*)d_in[0];
  const float* wih0 = (const float*)d_in[1];
  const float* whh0 = (const float*)d_in[2];
  const float* bih0 = (const float*)d_in[3];
  const float* bhh0 = (const float*)d_in[4];
  const float* wih1 = (const float*)d_in[5];
  const float* whh1 = (const float*)d_in[6];
  const float* bih1 = (const float*)d_in[7];
  const float* bhh1 = (const float*)d_in[8];
  const float* gamma = (const float*)d_in[9];
  const float* beta  = (const float*)d_in[10];
  const float* fcw   = (const float*)d_in[11];
  const float* fcb   = (const float*)d_in[12];

  const size_t HIST = (size_t)(TT + 1) * HD * 2;   // 33,556,480 B per history
  u64* h1u = (u64*)d_ws;
  u64* h2u = (u64*)((char*)d_ws + HIST);
  float* sums = (float*)((char*)d_ws + 2 * HIST);

  // slot 0 = h[-1] = 0 ; slots 1..TT = f16 NaN sentinel (0x7F7F)
  hipMemsetAsync(h1u, 0, (size_t)HD * 2, stream);
  hipMemsetAsync((char*)h1u + HD * 2, 0x7F, (size_t)TT * HD * 2, stream);
  hipMemsetAsync(h2u, 0, (size_t)HD * 2, stream);
  hipMemsetAsync((char*)h2u + HD * 2, 0x7F, (size_t)TT * HD * 2, stream);

  gru_persistent<<<64, 512, 0, stream>>>(x, wih0, whh0, bih0, bhh0,
                                         wih1, whh1, bih1, bhh1,
                                         h1u, h2u, sums);
  fc_bn_kernel<<<256, 256, 0, stream>>>((const unsigned*)h2u, sums, gamma, beta, fcw, fcb,
                                        (float*)d_out);
}

// Round 16
// 39489.606 us; speedup vs baseline: 2.0430x; 2.0430x over previous
//
#include <hip/hip_runtime.h>

// GRUModel: 2-layer GRU (T=16384, IN=512, H=1024) + BatchNorm(train) + FC(H->1)
//
// Persistent kernel, 128 blocks (64 layer0 + 64 layer1), 4 waves each; wave
// owns 4 contiguous channels (weights in VGPRs, v_dot2_f32_f16). Cross-block
// exchange via AGENT-scope relaxed atomics; consumers poll u64 granules
// against the f16-NaN sentinel 0x7F7F7F7F (memset 0x7F).
//
// ROUND-16 = EXACT REVERT TO R10 (best measured: 39.49ms, FETCH 485MB).
// Final law (R4-R15): the period is a serial cross-XCD handoff floor
// (store -> LLC visibility -> detect, ~1.5us) + compute (~0.7us). The R10
// configuration is the optimum of every axis tested:
//   - spin population: single-wave spin + park-at-barrier + LDS broadcast
//     on BOTH recurrences (R9: -24%, R10: -2.7%); further cuts via 8-wave
//     blocks regress (R15: 2 waves/SIMD serializes dots, period grows,
//     waiting spinners probe more -> FETCH doubles).
//   - spin form: all-4-reload do-while (masked/double-probe forms regress:
//     R7, R11 - probe rate up = congestion).
//   - spin placement: as late as possible, preceded by the h1-poll+ih-dots
//     arrival throttle (early starts regress: R8, R13).
//   - prefetch/merge of the usually-ready h1 poll: neutral or worse
//     (R12, R14 - the RT is already hidden under h2 arrival; R6 disaster).

#define TT 16384
#define IND 512
#define HD 1024

typedef _Float16 h2_t __attribute__((ext_vector_type(2)));
typedef unsigned long long u64;

static __device__ __forceinline__ float fdot2f(h2_t a, h2_t b, float c) {
  return __builtin_amdgcn_fdot2(a, b, c, false);
}
static __device__ __forceinline__ h2_t cvt2(float a, float b) {
  h2_t r; r.x = (_Float16)a; r.y = (_Float16)b; return r;
}
static __device__ __forceinline__ float sigm(float v) { return 1.f / (1.f + __expf(-v)); }
static __device__ __forceinline__ float tanh_f(float v) {
  v = fminf(fmaxf(v, -15.f), 15.f);
  float e = __expf(2.f * v);
  return (e - 1.f) / (e + 1.f);
}

// Reduce 4 per-lane partials across 64 lanes. Returns (R,Z,Nx,Nh) totals in
// all lanes. 11 cross-lane ops instead of 24 (pair-merge butterfly).
static __device__ __forceinline__ float4 reduce4(float aR, float aZ, float aNx,
                                                 float aNh, int lane) {
  const bool s1 = lane & 1;
  float x1 = s1 ? aZ : aR, y1 = s1 ? aR : aZ;
  x1 += __shfl_xor(y1, 1);
  float x2 = s1 ? aNh : aNx, y2 = s1 ? aNx : aNh;
  x2 += __shfl_xor(y2, 1);
  const bool s2 = lane & 2;
  float z = s2 ? x2 : x1, w = s2 ? x1 : x2;
  z += __shfl_xor(w, 2);
  z += __shfl_xor(z, 4);
  z += __shfl_xor(z, 8);
  z += __shfl_xor(z, 16);
  z += __shfl_xor(z, 32);
  return make_float4(__shfl(z, 0), __shfl(z, 1), __shfl(z, 2), __shfl(z, 3));
}

static __device__ __forceinline__ u64 pack4(float h0, float h1,
                                            float h2, float h3) {
  unsigned lo = (unsigned)__builtin_bit_cast(unsigned short, (_Float16)h0) |
                ((unsigned)__builtin_bit_cast(unsigned short, (_Float16)h1) << 16);
  unsigned hi = (unsigned)__builtin_bit_cast(unsigned short, (_Float16)h2) |
                ((unsigned)__builtin_bit_cast(unsigned short, (_Float16)h3) << 16);
  return (u64)lo | ((u64)hi << 32);
}

static __device__ __forceinline__ void unpack8(const u64 hv[4], h2_t hh[8]) {
#pragma unroll
  for (int i = 0; i < 4; ++i) {
    hh[2 * i]     = __builtin_bit_cast(h2_t, (unsigned)hv[i]);
    hh[2 * i + 1] = __builtin_bit_cast(h2_t, (unsigned)(hv[i] >> 32));
  }
}

static __device__ __forceinline__ u64 aload(const u64* p) {
  return __hip_atomic_load(p, __ATOMIC_RELAXED, __HIP_MEMORY_SCOPE_AGENT);
}

// Single-probe spin (R9/R10 proven form): all-4 reload until none sentinel.
static __device__ __forceinline__ void spin4(const u64* p, u64 v[4]) {
  bool ok;
  do {
    ok = true;
#pragma unroll
    for (int i = 0; i < 4; ++i) {
      v[i] = aload(p + i);
      ok = ok & ((unsigned)v[i] != 0x7F7F7F7Fu);
    }
  } while (__any(!ok));
}

__launch_bounds__(256, 1)
__global__ void gru_persistent(
    const float* __restrict__ x,
    const float* __restrict__ wih0, const float* __restrict__ whh0,
    const float* __restrict__ bih0, const float* __restrict__ bhh0,
    const float* __restrict__ wih1, const float* __restrict__ whh1,
    const float* __restrict__ bih1, const float* __restrict__ bhh1,
    u64* h1u, u64* h2u, float* sums)
{
  __shared__ u64 bcast[2][256];  // double-buffered broadcast slab (both layers)
  const int bid = blockIdx.x;
  const int tid = threadIdx.x;
  const int wave = tid >> 6;
  const int lane = tid & 63;

  if (bid < 64) {
    // ---------------- layer 0 : wave owns channels ch..ch+3 ----------------
    const int ch = bid * 16 + wave * 4;
    h2_t Wx[4][3][4];   // x-part: 8 f16 per gate per channel
    h2_t Wh[4][3][8];   // h-part: 16 f16 per gate per channel
    float bRv[4], bZv[4], bNxv[4], bNhv[4];
#pragma unroll
    for (int cc = 0; cc < 4; ++cc) {
      const int c = ch + cc;
#pragma unroll
      for (int g = 0; g < 3; ++g) {
        const float* pr = wih0 + (size_t)(g * HD + c) * IND + 8 * lane;
#pragma unroll
        for (int j = 0; j < 4; ++j) Wx[cc][g][j] = cvt2(pr[2 * j], pr[2 * j + 1]);
        const float* ph = whh0 + (size_t)(g * HD + c) * HD + 16 * lane;
#pragma unroll
        for (int j = 0; j < 8; ++j) Wh[cc][g][j] = cvt2(ph[2 * j], ph[2 * j + 1]);
      }
      bRv[cc]  = bih0[c] + bhh0[c];
      bZv[cc]  = bih0[HD + c] + bhh0[HD + c];
      bNxv[cc] = bih0[2 * HD + c];
      bNhv[cc] = bhh0[2 * HD + c];
    }
    float hprev[4] = {0.f, 0.f, 0.f, 0.f};
    // software-pipelined x row
    const float* px0 = x + 8 * lane;
    float4 xa = *(const float4*)px0;
    float4 xb = *(const float4*)(px0 + 4);
    for (int t = 0; t < TT; ++t) {
      h2_t xv[4];
      xv[0] = cvt2(xa.x, xa.y); xv[1] = cvt2(xa.z, xa.w);
      xv[2] = cvt2(xb.x, xb.y); xv[3] = cvt2(xb.z, xb.w);
      if (t + 1 < TT) {
        const float* pn = x + (size_t)(t + 1) * IND + 8 * lane;
        xa = *(const float4*)pn;
        xb = *(const float4*)(pn + 4);
      }
      // x-part partials (off critical path, all waves; also the arrival
      // throttle before wave0's spin)
      float aR[4], aZ[4], aNx[4], aNh[4];
#pragma unroll
      for (int cc = 0; cc < 4; ++cc) {
        float r = 0.f, z = 0.f, n = 0.f;
#pragma unroll
        for (int j = 0; j < 4; ++j) {
          r = fdot2f(Wx[cc][0][j], xv[j], r);
          z = fdot2f(Wx[cc][1][j], xv[j], z);
          n = fdot2f(Wx[cc][2][j], xv[j], n);
        }
        aR[cc] = r; aZ[cc] = z; aNx[cc] = n; aNh[cc] = 0.f;
      }
      // h1[t-1] (slot t; slot 0 pre-zeroed): single-wave spin + broadcast;
      // waves 1-3 park at the barrier.
      u64 hv[4];
      if (wave == 0) {
        spin4(h1u + (size_t)t * 256 + 4 * lane, hv);
#pragma unroll
        for (int i = 0; i < 4; ++i) bcast[t & 1][4 * lane + i] = hv[i];
      }
      __syncthreads();
      if (wave != 0) {
#pragma unroll
        for (int i = 0; i < 4; ++i) hv[i] = bcast[t & 1][4 * lane + i];
      }
      h2_t hh[8];
      unpack8(hv, hh);
#pragma unroll
      for (int cc = 0; cc < 4; ++cc) {
        float r = aR[cc], z = aZ[cc], n = aNh[cc];
#pragma unroll
        for (int j = 0; j < 8; ++j) {
          r = fdot2f(Wh[cc][0][j], hh[j], r);
          z = fdot2f(Wh[cc][1][j], hh[j], z);
          n = fdot2f(Wh[cc][2][j], hh[j], n);
        }
        aR[cc] = r; aZ[cc] = z; aNh[cc] = n;
      }
      float hn[4];
#pragma unroll
      for (int cc = 0; cc < 4; ++cc) {
        float4 s = reduce4(aR[cc], aZ[cc], aNx[cc], aNh[cc], lane);
        float r = sigm(s.x + bRv[cc]);
        float zz = sigm(s.y + bZv[cc]);
        float n = tanh_f(s.z + bNxv[cc] + r * (s.w + bNhv[cc]));
        hn[cc] = (1.f - zz) * n + zz * hprev[cc];
        hprev[cc] = hn[cc];
      }
      if (lane == 0) {
        u64 pk = pack4(hn[0], hn[1], hn[2], hn[3]);
        __hip_atomic_store(h1u + (size_t)(t + 1) * 256 + (ch >> 2), pk,
                           __ATOMIC_RELAXED, __HIP_MEMORY_SCOPE_AGENT);
      }
    }
  } else {
    // ---------------- layer 1 : wave owns channels ch..ch+3 ----------------
    const int ch = (bid - 64) * 16 + wave * 4;
    // parts: 0=r_ih 1=r_hh 2=z_ih 3=z_hh 4=n_ih 5=n_hh ; 16-f16 slice each
    h2_t W[4][6][8];
    float bRv[4], bZv[4], bNxv[4], bNhv[4];
#pragma unroll
    for (int cc = 0; cc < 4; ++cc) {
      const int c = ch + cc;
#pragma unroll
      for (int g = 0; g < 3; ++g) {
        const float* pi = wih1 + (size_t)(g * HD + c) * HD + 16 * lane;
        const float* ph = whh1 + (size_t)(g * HD + c) * HD + 16 * lane;
#pragma unroll
        for (int j = 0; j < 8; ++j) {
          W[cc][2 * g][j]     = cvt2(pi[2 * j], pi[2 * j + 1]);
          W[cc][2 * g + 1][j] = cvt2(ph[2 * j], ph[2 * j + 1]);
        }
      }
      bRv[cc]  = bih1[c] + bhh1[c];
      bZv[cc]  = bih1[HD + c] + bhh1[HD + c];
      bNxv[cc] = bih1[2 * HD + c];
      bNhv[cc] = bhh1[2 * HD + c];
    }
    float hprev[4] = {0.f, 0.f, 0.f, 0.f};
    float ssum[4] = {0.f, 0.f, 0.f, 0.f};
    float ssq[4] = {0.f, 0.f, 0.f, 0.f};
    for (int t = 1; t <= TT; ++t) {
      // poll h1[t-1] (slot t) — per-wave baseline form (usually 1 iteration;
      // doubles as the arrival throttle before wave0's h2 spin)
      const u64* p1 = h1u + (size_t)t * 256 + 4 * lane;
      u64 va[4];
      bool ok;
      do {
        ok = true;
#pragma unroll
        for (int i = 0; i < 4; ++i) {
          va[i] = aload(p1 + i);
          ok = ok & ((unsigned)va[i] != 0x7F7F7F7Fu);
        }
      } while (__any(!ok));
      h2_t g1[8];
      unpack8(va, g1);
      float aR[4], aZ[4], aNx[4], aNh[4];
#pragma unroll
      for (int cc = 0; cc < 4; ++cc) {
        float r = 0.f, z = 0.f, n = 0.f;
#pragma unroll
        for (int j = 0; j < 8; ++j) {
          r = fdot2f(W[cc][0][j], g1[j], r);
          z = fdot2f(W[cc][2][j], g1[j], z);
          n = fdot2f(W[cc][4][j], g1[j], n);
        }
        aR[cc] = r; aZ[cc] = z; aNx[cc] = n; aNh[cc] = 0.f;
      }
      // h2[t-2] (slot t-1): single-wave spin (R10 form/placement) + broadcast;
      // waves 1-3 park at the barrier.
      u64 vb[4];
      if (wave == 0) {
        spin4(h2u + (size_t)(t - 1) * 256 + 4 * lane, vb);
#pragma unroll
        for (int i = 0; i < 4; ++i) bcast[t & 1][4 * lane + i] = vb[i];
      }
      __syncthreads();
      if (wave != 0) {
#pragma unroll
        for (int i = 0; i < 4; ++i) vb[i] = bcast[t & 1][4 * lane + i];
      }
      h2_t g2[8];
      unpack8(vb, g2);
#pragma unroll
      for (int cc = 0; cc < 4; ++cc) {
        float r = aR[cc], z = aZ[cc], n = aNh[cc];
#pragma unroll
        for (int j = 0; j < 8; ++j) {
          r = fdot2f(W[cc][1][j], g2[j], r);
          z = fdot2f(W[cc][3][j], g2[j], z);
          n = fdot2f(W[cc][5][j], g2[j], n);
        }
        aR[cc] = r; aZ[cc] = z; aNh[cc] = n;
      }
      float hn[4];
#pragma unroll
      for (int cc = 0; cc < 4; ++cc) {
        float4 s = reduce4(aR[cc], aZ[cc], aNx[cc], aNh[cc], lane);
        float r = sigm(s.x + bRv[cc]);
        float zz = sigm(s.y + bZv[cc]);
        float n = tanh_f(s.z + bNxv[cc] + r * (s.w + bNhv[cc]));
        hn[cc] = (1.f - zz) * n + zz * hprev[cc];
        hprev[cc] = hn[cc];
        ssum[cc] += hn[cc];
        ssq[cc] += hn[cc] * hn[cc];
      }
      if (lane == 0) {
        u64 pk = pack4(hn[0], hn[1], hn[2], hn[3]);
        __hip_atomic_store(h2u + (size_t)t * 256 + (ch >> 2), pk,
                           __ATOMIC_RELAXED, __HIP_MEMORY_SCOPE_AGENT);
      }
    }
    if (lane == 0) {
#pragma unroll
      for (int cc = 0; cc < 4; ++cc) {
        sums[ch + cc] = ssum[cc];
        sums[HD + ch + cc] = ssq[cc];
      }
    }
  }
}

// y[t] = K + sum_c h2[t,c]*A[c];  A = rsqrt(var+eps)*gamma*fc_w,
// K = fc_b + sum_c (beta*fc_w - mu*A)
__launch_bounds__(256)
__global__ void fc_bn_kernel(const unsigned* __restrict__ h2u, const float* __restrict__ sums,
                             const float* __restrict__ gamma, const float* __restrict__ beta,
                             const float* __restrict__ fcw, const float* __restrict__ fcb,
                             float* __restrict__ out)
{
  const int tid = threadIdx.x;
  const int wave = tid >> 6;
  const int lane = tid & 63;
  float A[16];
  float kp = 0.f;
#pragma unroll
  for (int j = 0; j < 16; ++j) {
    const int c = 16 * lane + j;
    float mu = sums[c] * (1.f / TT);
    float var = fmaxf(sums[HD + c] * (1.f / TT) - mu * mu, 0.f);
    float rs = rsqrtf(var + 1e-5f);
    float a = rs * gamma[c] * fcw[c];
    A[j] = a;
    kp += beta[c] * fcw[c] - mu * a;
  }
#pragma unroll
  for (int m = 32; m >= 1; m >>= 1) kp += __shfl_xor(kp, m);
  const float K = kp + fcb[0];
  const int tbase = (blockIdx.x * 4 + wave) * 16;
  for (int mm = 0; mm < 16; ++mm) {
    const int t = tbase + mm;
    const unsigned* p = h2u + (size_t)(t + 1) * 512 + 8 * lane;
    float d = 0.f;
#pragma unroll
    for (int j = 0; j < 8; ++j) {
      h2_t hp = __builtin_bit_cast(h2_t, p[j]);
      d += (float)hp.x * A[2 * j] + (float)hp.y * A[2 * j + 1];
    }
#pragma unroll
    for (int m = 32; m >= 1; m >>= 1) d += __shfl_xor(d, m);
    if (lane == 0) out[t] = K + d;
  }
}

extern "C" void kernel_launch(void* const* d_in, const int* in_sizes, int n_in,
                              void* d_out, int out_size, void* d_ws, size_t ws_size,
                              hipStream_t stream) {
  const float* x    = (const float*)d_in[0];
  const float* wih0 = (const float*)d_in[1];
  const float* whh0 = (const float*)d_in[2];
  const float* bih0 = (const float*)d_in[3];
  const float* bhh0 = (const float*)d_in[4];
  const float* wih1 = (const float*)d_in[5];
  const float* whh1 = (const float*)d_in[6];
  const float* bih1 = (const float*)d_in[7];
  const float* bhh1 = (const float*)d_in[8];
  const float* gamma = (const float*)d_in[9];
  const float* beta  = (const float*)d_in[10];
  const float* fcw   = (const float*)d_in[11];
  const float* fcb   = (const float*)d_in[12];

  const size_t HIST = (size_t)(TT + 1) * HD * 2;   // 33,556,480 B per history
  u64* h1u = (u64*)d_ws;
  u64* h2u = (u64*)((char*)d_ws + HIST);
  float* sums = (float*)((char*)d_ws + 2 * HIST);

  // slot 0 = h[-1] = 0 ; slots 1..TT = f16 NaN sentinel (0x7F7F)
  hipMemsetAsync(h1u, 0, (size_t)HD * 2, stream);
  hipMemsetAsync((char*)h1u + HD * 2, 0x7F, (size_t)TT * HD * 2, stream);
  hipMemsetAsync(h2u, 0, (size_t)HD * 2, stream);
  hipMemsetAsync((char*)h2u + HD * 2, 0x7F, (size_t)TT * HD * 2, stream);

  gru_persistent<<<128, 256, 0, stream>>>(x, wih0, whh0, bih0, bhh0,
                                          wih1, whh1, bih1, bhh1,
                                          h1u, h2u, sums);
  fc_bn_kernel<<<256, 256, 0, stream>>>((const unsigned*)h2u, sums, gamma, beta, fcw, fcb,
                                        (float*)d_out);
}